// Round 1
// baseline (122.149 us; speedup 1.0000x reference)
//
#include <hip/hip_runtime.h>

typedef float  f4v   __attribute__((ext_vector_type(4)));
typedef float  f32x4 __attribute__((ext_vector_type(4)));
typedef short  s8v   __attribute__((ext_vector_type(8)));
typedef short  s4v   __attribute__((ext_vector_type(4)));
typedef __bf16 bf16x8 __attribute__((ext_vector_type(8)));

#define N_   197
#define H_   12
#define CIN  3072
#define COUT 1024

__device__ __forceinline__ unsigned short f2bf(float f) {
    unsigned u = __float_as_uint(f);
    u += 0x7FFFu + ((u >> 16) & 1u);
    return (unsigned short)(u >> 16);
}
__device__ __forceinline__ float bf2f(unsigned short s) {
    return __uint_as_float(((unsigned)s) << 16);
}
__device__ __forceinline__ f32x4 mfma_bf16(s8v a, s8v b, f32x4 c) {
    return __builtin_amdgcn_mfma_f32_16x16x32_bf16(
        __builtin_bit_cast(bf16x8, a), __builtin_bit_cast(bf16x8, b), c, 0, 0, 0);
}

// One block per (b,h). 256 threads = 4 waves, each wave owns 16-row query tiles.
// LDS: K_ext[272 rows][72] bf16 (rows 0..196 K, 208..237 tk_v, 240..269 tk_h, rest 0)
//      Vt[64 d][288 j]  bf16 (j 0..196 V, 208..237 tv_v, 240..269 tv_h, rest 0)
//      Pm[wave][16 m][288 j] bf16 (j 0..207 P, 208..239 wv bins, 240..271 wh bins, 272..287 0)
//      qt[wave][16][66] f32  (cols 0..31 qtv, 32..63 qth)
__launch_bounds__(256, 1)
__global__ void attn_super(const float* __restrict__ x,
                           const float* __restrict__ tkv,
                           const float* __restrict__ tkh,
                           const float* __restrict__ tvv,
                           const float* __restrict__ tvh,
                           float* __restrict__ out) {
    __shared__ __align__(16) unsigned short Kl[272 * 72];
    __shared__ __align__(16) unsigned short Vt[64 * 288];
    __shared__ __align__(16) unsigned short Pm[4][16 * 288];
    __shared__ float qt[4][16 * 66];

    const int bid = blockIdx.x;
    const int b = bid / H_, h = bid % H_;
    const int tid = threadIdx.x;
    const int w  = tid >> 6;
    const int l  = tid & 63;
    const int lg = l >> 4;   // 16-lane group
    const int ln = l & 15;

    const float* xb = x + (size_t)b * N_ * CIN;

    // ---- zero-pad output channels [768,1024) (done by h<4 blocks) ----
    if (h < 4) {
        float* oz = out + (size_t)b * N_ * COUT + 768 + h * 64;
        for (int idx = tid; idx < N_ * 16; idx += 256) {
            int row = idx >> 4, c4 = idx & 15;
            f4v z = {0.f, 0.f, 0.f, 0.f};
            *(f4v*)(oz + (size_t)row * COUT + c4 * 4) = z;
        }
    }

    // ---- stage K_ext (row-major, stride 72 shorts) ----
    for (int it = 0; it < 17; ++it) {
        int idx = it * 256 + tid;          // 272*16 = 4352 exactly
        int row = idx >> 4, c4 = idx & 15;
        int d0 = c4 * 4;
        f4v v = {0.f, 0.f, 0.f, 0.f};
        if (row < N_)                       v = *(const f4v*)(xb + (size_t)row * CIN + 768 + h * 64 + d0);
        else if (row >= 208 && row < 238)   v = *(const f4v*)(tkv + (row - 208) * 64 + d0);
        else if (row >= 240 && row < 270)   v = *(const f4v*)(tkh + (row - 240) * 64 + d0);
        s4v pk;
        pk[0] = (short)f2bf(v[0]); pk[1] = (short)f2bf(v[1]);
        pk[2] = (short)f2bf(v[2]); pk[3] = (short)f2bf(v[3]);
        *(s4v*)(&Kl[row * 72 + d0]) = pk;
    }
    // ---- stage Vt (transposed, j consecutive across lanes) ----
    for (int it = 0; it < 18; ++it) {
        int idx = it * 256 + tid;          // 288*16 = 4608 exactly
        int j = idx % 288, ch = idx / 288;
        int d0 = ch * 4;
        f4v v = {0.f, 0.f, 0.f, 0.f};
        if (j < N_)                         v = *(const f4v*)(xb + (size_t)j * CIN + 1536 + h * 64 + d0);
        else if (j >= 208 && j < 238)       v = *(const f4v*)(tvv + (j - 208) * 64 + d0);
        else if (j >= 240 && j < 270)       v = *(const f4v*)(tvh + (j - 240) * 64 + d0);
        #pragma unroll
        for (int e = 0; e < 4; ++e)
            Vt[(d0 + e) * 288 + j] = f2bf(v[e]);
    }
    __syncthreads();

    for (int q0 = w; q0 < 13; q0 += 4) {
        const int qb = q0 * 16;
        // Q A-fragments straight from global (pre-scaled by 1/8), rows clamped
        int qrow = qb + ln; if (qrow > 196) qrow = 196;
        const float* qp = xb + (size_t)qrow * CIN + h * 64;
        s8v aq[2];
        #pragma unroll
        for (int s = 0; s < 2; ++s) {
            f4v q1 = *(const f4v*)(qp + s * 32 + lg * 8);
            f4v q2 = *(const f4v*)(qp + s * 32 + lg * 8 + 4);
            #pragma unroll
            for (int e = 0; e < 4; ++e) {
                aq[s][e]     = (short)f2bf(q1[e] * 0.125f);
                aq[s][e + 4] = (short)f2bf(q2[e] * 0.125f);
            }
        }
        // per C-frag-row rel-pos constants
        int ri[4], ci[4];
        #pragma unroll
        for (int r = 0; r < 4; ++r) {
            int i = qb + lg * 4 + r;
            int im1 = i - 1; if (im1 < 0) im1 = 0;
            ri[r] = im1 / 14; ci[r] = im1 - ri[r] * 14;
        }
        // table tiles (ct 13..16) -> qtv/qth into qt[]
        #pragma unroll
        for (int ct = 13; ct < 17; ++ct) {
            f32x4 acc = {0.f, 0.f, 0.f, 0.f};
            #pragma unroll
            for (int s = 0; s < 2; ++s) {
                const s8v bk = *(const s8v*)(&Kl[(ct * 16 + ln) * 72 + s * 32 + lg * 8]);
                acc = mfma_bf16(aq[s], bk, acc);
            }
            int cc = (ct - 13) * 16 + ln;
            #pragma unroll
            for (int r = 0; r < 4; ++r)
                qt[w][(lg * 4 + r) * 66 + cc] = acc[r];
        }
        // main tiles with fused bias + exp
        float rs[4] = {0.f, 0.f, 0.f, 0.f};
        for (int ct = 0; ct < 13; ++ct) {
            f32x4 acc = {0.f, 0.f, 0.f, 0.f};
            #pragma unroll
            for (int s = 0; s < 2; ++s) {
                const s8v bk = *(const s8v*)(&Kl[(ct * 16 + ln) * 72 + s * 32 + lg * 8]);
                acc = mfma_bf16(aq[s], bk, acc);
            }
            int jj = ct * 16 + ln;
            int mj = (jj - 1) / 14;            // jj==0 case masked below
            int cj = (jj - 1) - mj * 14;
            bool jv = (jj < N_);
            #pragma unroll
            for (int r = 0; r < 4; ++r) {
                int i = qb + lg * 4 + r;
                bool z = (i == 0) || (jj == 0);
                int t = z ? 0 : (mj - ri[r] + 15);
                int u = z ? 32 : (cj - ci[r] + 15 + 32);
                float bias = qt[w][(lg * 4 + r) * 66 + t] + qt[w][(lg * 4 + r) * 66 + u];
                float p = __expf(acc[r] + bias);
                p = jv ? p : 0.f;
                rs[r] += p;
                Pm[w][(lg * 4 + r) * 288 + jj] = f2bf(p);
            }
        }
        // row sums (reduce across the 16-lane col dim)
        #pragma unroll
        for (int r = 0; r < 4; ++r) {
            float v = rs[r];
            v += __shfl_xor(v, 1); v += __shfl_xor(v, 2);
            v += __shfl_xor(v, 4); v += __shfl_xor(v, 8);
            rs[r] = v;
        }
        // zero bin region j in [208,288)
        #pragma unroll
        for (int z5 = 0; z5 < 5; ++z5) {
            int s = z5 * 64 + l;               // 0..319
            int row = s / 20, cg = s - row * 20;
            s4v z = {0, 0, 0, 0};
            *(s4v*)(&Pm[w][row * 288 + 208 + cg * 4]) = z;
        }
        // bin tasks: row m = ln, i = qb+ln
        {
            bool row0 = (qb + ln == 0);
            int im1 = qb + ln - 1; if (im1 < 0) im1 = 0;
            int rit = im1 / 14, cit = im1 - rit * 14;
            const unsigned short* pr = &Pm[w][ln * 288];
            unsigned short* bw = &Pm[w][ln * 288];
            #pragma unroll
            for (int st = 0; st < 4; ++st) {   // wv: segment sums of 14
                int mrun = lg + st * 4;
                if (mrun < 14 && !row0) {
                    float sum = 0.f;
                    #pragma unroll
                    for (int e = 0; e < 14; ++e) sum += bf2f(pr[1 + 14 * mrun + e]);
                    bw[208 + (mrun - rit + 15)] = f2bf(sum);
                }
            }
            #pragma unroll
            for (int st = 0; st < 4; ++st) {   // wh: stride-14 sums
                int c = lg + st * 4;
                if (c < 14 && !row0) {
                    float sum = 0.f;
                    #pragma unroll
                    for (int e = 0; e < 14; ++e) sum += bf2f(pr[1 + 14 * e + c]);
                    bw[240 + (c - cit + 15)] = f2bf(sum);
                }
            }
            if (lg == 0 && !row0) {            // j==0 column -> bin 0
                unsigned short p0 = pr[0];
                bw[208] = p0;
                bw[240] = p0;
            }
        }
        if (q0 == 0 && l == 0) {               // i==0 row: everything to bin 0
            unsigned short rb = f2bf(rs[0]);
            Pm[w][208] = rb;
            Pm[w][240] = rb;
        }
        // PV over j in [0,288): P@V + wv@tv_v + wh@tv_h
        f32x4 oacc[4];
        #pragma unroll
        for (int nt = 0; nt < 4; ++nt) { f32x4 z = {0.f,0.f,0.f,0.f}; oacc[nt] = z; }
        for (int kt = 0; kt < 9; ++kt) {
            const s8v ap = *(const s8v*)(&Pm[w][ln * 288 + kt * 32 + lg * 8]);
            #pragma unroll
            for (int nt = 0; nt < 4; ++nt) {
                const s8v bv = *(const s8v*)(&Vt[(nt * 16 + ln) * 288 + kt * 32 + lg * 8]);
                oacc[nt] = mfma_bf16(ap, bv, oacc[nt]);
            }
        }
        // normalize + store
        #pragma unroll
        for (int r = 0; r < 4; ++r) {
            int n = qb + lg * 4 + r;
            if (n < N_) {
                float sc = 1.0f / rs[r];
                float* orow = out + ((size_t)b * N_ + n) * COUT + h * 64;
                #pragma unroll
                for (int nt = 0; nt < 4; ++nt)
                    orow[nt * 16 + ln] = oacc[nt][r] * sc;
            }
        }
    }
}

extern "C" void kernel_launch(void* const* d_in, const int* in_sizes, int n_in,
                              void* d_out, int out_size, void* d_ws, size_t ws_size,
                              hipStream_t stream) {
    const float* x   = (const float*)d_in[0];
    const float* tkv = (const float*)d_in[1];
    const float* tkh = (const float*)d_in[2];
    const float* tvv = (const float*)d_in[3];
    const float* tvh = (const float*)d_in[4];
    float* o = (float*)d_out;
    attn_super<<<dim3(64 * H_), dim3(256), 0, stream>>>(x, tkv, tkh, tvv, tvh, o);
}

// Round 2
// 117.266 us; speedup vs baseline: 1.0416x; 1.0416x over previous
//
#include <hip/hip_runtime.h>

typedef float  f4v   __attribute__((ext_vector_type(4)));
typedef float  f32x4 __attribute__((ext_vector_type(4)));
typedef short  s8v   __attribute__((ext_vector_type(8)));
typedef short  s4v   __attribute__((ext_vector_type(4)));
typedef __bf16 bf16x8 __attribute__((ext_vector_type(8)));

#define N_   197
#define H_   12
#define CIN  3072
#define COUT 1024
#define PJ   292   // padded row stride for Vt/Pm (146 dwords % 32 = 18 -> conflict-free)

__device__ __forceinline__ unsigned short f2bf(float f) {
    unsigned u = __float_as_uint(f);
    u += 0x7FFFu + ((u >> 16) & 1u);
    return (unsigned short)(u >> 16);
}
__device__ __forceinline__ float bf2f(unsigned short s) {
    return __uint_as_float(((unsigned)s) << 16);
}
__device__ __forceinline__ f32x4 mfma_bf16(s8v a, s8v b, f32x4 c) {
    return __builtin_amdgcn_mfma_f32_16x16x32_bf16(
        __builtin_bit_cast(bf16x8, a), __builtin_bit_cast(bf16x8, b), c, 0, 0, 0);
}

// One block per (b,h). 256 threads = 4 waves, each wave owns 16-row query tiles.
// LDS: Kl[272 rows][72] bf16 (rows 0..196 K, 208..237 tk_v, 240..269 tk_h, rest 0)
//      Vt[64 d][PJ]  bf16 (j 0..196 V, 208..237 tv_v, 240..269 tv_h, rest 0; cols<288 read)
//      Pm[wave][16 m][PJ] bf16 (j 0..207 P, 208..239 wv bins, 240..271 wh bins, 272..287 0)
//      qt[wave][16][66] f32  (cols 0..31 qtv, 32..63 qth)
__launch_bounds__(256, 1)
__global__ void attn_super(const float* __restrict__ x,
                           const float* __restrict__ tkv,
                           const float* __restrict__ tkh,
                           const float* __restrict__ tvv,
                           const float* __restrict__ tvh,
                           float* __restrict__ out) {
    __shared__ __align__(16) unsigned short Kl[272 * 72];
    __shared__ __align__(16) unsigned short Vt[64 * PJ];
    __shared__ __align__(16) unsigned short Pm[4][16 * PJ];
    __shared__ float qt[4][16 * 66];

    const int bid = blockIdx.x;
    const int b = bid / H_, h = bid % H_;
    const int tid = threadIdx.x;
    const int w  = tid >> 6;
    const int l  = tid & 63;
    const int lg = l >> 4;   // 16-lane group
    const int ln = l & 15;

    const float* xb = x + (size_t)b * N_ * CIN;

    // ---- zero-pad output channels [768,1024) (done by h<4 blocks) ----
    if (h < 4) {
        float* oz = out + (size_t)b * N_ * COUT + 768 + h * 64;
        for (int idx = tid; idx < N_ * 16; idx += 256) {
            int row = idx >> 4, c4 = idx & 15;
            f4v z = {0.f, 0.f, 0.f, 0.f};
            *(f4v*)(oz + (size_t)row * COUT + c4 * 4) = z;
        }
    }

    // ---- stage K_ext (row-major, stride 72 shorts) ----
    for (int it = 0; it < 17; ++it) {
        int idx = it * 256 + tid;          // 272*16 = 4352 exactly
        int row = idx >> 4, c4 = idx & 15;
        int d0 = c4 * 4;
        f4v v = {0.f, 0.f, 0.f, 0.f};
        if (row < N_)                       v = *(const f4v*)(xb + (size_t)row * CIN + 768 + h * 64 + d0);
        else if (row >= 208 && row < 238)   v = *(const f4v*)(tkv + (row - 208) * 64 + d0);
        else if (row >= 240 && row < 270)   v = *(const f4v*)(tkh + (row - 240) * 64 + d0);
        s4v pk;
        pk[0] = (short)f2bf(v[0]); pk[1] = (short)f2bf(v[1]);
        pk[2] = (short)f2bf(v[2]); pk[3] = (short)f2bf(v[3]);
        *(s4v*)(&Kl[row * 72 + d0]) = pk;
    }
    // ---- stage Vt (transposed, j consecutive across lanes) ----
    for (int it = 0; it < 18; ++it) {
        int idx = it * 256 + tid;          // 288*16 = 4608 exactly
        int j = idx % 288, ch = idx / 288;
        int d0 = ch * 4;
        f4v v = {0.f, 0.f, 0.f, 0.f};
        if (j < N_)                         v = *(const f4v*)(xb + (size_t)j * CIN + 1536 + h * 64 + d0);
        else if (j >= 208 && j < 238)       v = *(const f4v*)(tvv + (j - 208) * 64 + d0);
        else if (j >= 240 && j < 270)       v = *(const f4v*)(tvh + (j - 240) * 64 + d0);
        #pragma unroll
        for (int e = 0; e < 4; ++e)
            Vt[(d0 + e) * PJ + j] = f2bf(v[e]);
    }
    __syncthreads();

    for (int q0 = w; q0 < 13; q0 += 4) {
        const int qb = q0 * 16;
        // Q A-fragments straight from global (pre-scaled by 1/8), rows clamped
        int qrow = qb + ln; if (qrow > 196) qrow = 196;
        const float* qp = xb + (size_t)qrow * CIN + h * 64;
        s8v aq[2];
        #pragma unroll
        for (int s = 0; s < 2; ++s) {
            f4v q1 = *(const f4v*)(qp + s * 32 + lg * 8);
            f4v q2 = *(const f4v*)(qp + s * 32 + lg * 8 + 4);
            #pragma unroll
            for (int e = 0; e < 4; ++e) {
                aq[s][e]     = (short)f2bf(q1[e] * 0.125f);
                aq[s][e + 4] = (short)f2bf(q2[e] * 0.125f);
            }
        }
        // per C-frag-row rel-pos constants
        int ri[4], ci[4];
        #pragma unroll
        for (int r = 0; r < 4; ++r) {
            int i = qb + lg * 4 + r;
            int im1 = i - 1; if (im1 < 0) im1 = 0;
            ri[r] = im1 / 14; ci[r] = im1 - ri[r] * 14;
        }
        // table tiles (ct 13..16) -> qtv/qth into qt[]
        #pragma unroll
        for (int ct = 13; ct < 17; ++ct) {
            f32x4 acc = {0.f, 0.f, 0.f, 0.f};
            #pragma unroll
            for (int s = 0; s < 2; ++s) {
                const s8v bk = *(const s8v*)(&Kl[(ct * 16 + ln) * 72 + s * 32 + lg * 8]);
                acc = mfma_bf16(aq[s], bk, acc);
            }
            int cc = (ct - 13) * 16 + ln;
            #pragma unroll
            for (int r = 0; r < 4; ++r)
                qt[w][(lg * 4 + r) * 66 + cc] = acc[r];
        }
        // main tiles with fused bias + exp
        float rs[4] = {0.f, 0.f, 0.f, 0.f};
        for (int ct = 0; ct < 13; ++ct) {
            f32x4 acc = {0.f, 0.f, 0.f, 0.f};
            #pragma unroll
            for (int s = 0; s < 2; ++s) {
                const s8v bk = *(const s8v*)(&Kl[(ct * 16 + ln) * 72 + s * 32 + lg * 8]);
                acc = mfma_bf16(aq[s], bk, acc);
            }
            int jj = ct * 16 + ln;
            int mj = (jj - 1) / 14;            // jj==0 case masked below
            int cj = (jj - 1) - mj * 14;
            bool jv = (jj < N_);
            #pragma unroll
            for (int r = 0; r < 4; ++r) {
                int i = qb + lg * 4 + r;
                bool z = (i == 0) || (jj == 0);
                int t = z ? 0 : (mj - ri[r] + 15);
                int u = z ? 32 : (cj - ci[r] + 15 + 32);
                float bias = qt[w][(lg * 4 + r) * 66 + t] + qt[w][(lg * 4 + r) * 66 + u];
                float p = __expf(acc[r] + bias);
                p = jv ? p : 0.f;
                rs[r] += p;
                Pm[w][(lg * 4 + r) * PJ + jj] = f2bf(p);
            }
        }
        // row sums (reduce across the 16-lane col dim)
        #pragma unroll
        for (int r = 0; r < 4; ++r) {
            float v = rs[r];
            v += __shfl_xor(v, 1); v += __shfl_xor(v, 2);
            v += __shfl_xor(v, 4); v += __shfl_xor(v, 8);
            rs[r] = v;
        }
        // zero bin region j in [208,292): 84 cols = 21 s4v per row, 16 rows = 336 tasks
        for (int s = l; s < 336; s += 64) {
            int row = s / 21, cg = s - row * 21;
            s4v z = {0, 0, 0, 0};
            *(s4v*)(&Pm[w][row * PJ + 208 + cg * 4]) = z;
        }
        // bin tasks: row m = ln, i = qb+ln
        {
            bool row0 = (qb + ln == 0);
            int im1 = qb + ln - 1; if (im1 < 0) im1 = 0;
            int rit = im1 / 14, cit = im1 - rit * 14;
            const unsigned short* pr = &Pm[w][ln * PJ];
            unsigned short* bw = &Pm[w][ln * PJ];
            #pragma unroll
            for (int st = 0; st < 4; ++st) {   // wv: segment sums of 14
                int mrun = lg + st * 4;
                if (mrun < 14 && !row0) {
                    float sum = 0.f;
                    #pragma unroll
                    for (int e = 0; e < 14; ++e) sum += bf2f(pr[1 + 14 * mrun + e]);
                    bw[208 + (mrun - rit + 15)] = f2bf(sum);
                }
            }
            #pragma unroll
            for (int st = 0; st < 4; ++st) {   // wh: stride-14 sums
                int c = lg + st * 4;
                if (c < 14 && !row0) {
                    float sum = 0.f;
                    #pragma unroll
                    for (int e = 0; e < 14; ++e) sum += bf2f(pr[1 + 14 * e + c]);
                    bw[240 + (c - cit + 15)] = f2bf(sum);
                }
            }
            if (lg == 0 && !row0) {            // j==0 column -> bin 0
                unsigned short p0 = pr[0];
                bw[208] = p0;
                bw[240] = p0;
            }
        }
        if (q0 == 0 && l == 0) {               // i==0 row: everything to bin 0
            unsigned short rb = f2bf(rs[0]);
            Pm[w][208] = rb;
            Pm[w][240] = rb;
        }
        // PV over j in [0,288): P@V + wv@tv_v + wh@tv_h
        f32x4 oacc[4];
        #pragma unroll
        for (int nt = 0; nt < 4; ++nt) { f32x4 z = {0.f,0.f,0.f,0.f}; oacc[nt] = z; }
        for (int kt = 0; kt < 9; ++kt) {
            const s8v ap = *(const s8v*)(&Pm[w][ln * PJ + kt * 32 + lg * 8]);
            #pragma unroll
            for (int nt = 0; nt < 4; ++nt) {
                const s8v bv = *(const s8v*)(&Vt[(nt * 16 + ln) * PJ + kt * 32 + lg * 8]);
                oacc[nt] = mfma_bf16(ap, bv, oacc[nt]);
            }
        }
        // normalize + store
        #pragma unroll
        for (int r = 0; r < 4; ++r) {
            int n = qb + lg * 4 + r;
            if (n < N_) {
                float sc = 1.0f / rs[r];
                float* orow = out + ((size_t)b * N_ + n) * COUT + h * 64;
                #pragma unroll
                for (int nt = 0; nt < 4; ++nt)
                    orow[nt * 16 + ln] = oacc[nt][r] * sc;
            }
        }
    }
}

extern "C" void kernel_launch(void* const* d_in, const int* in_sizes, int n_in,
                              void* d_out, int out_size, void* d_ws, size_t ws_size,
                              hipStream_t stream) {
    const float* x   = (const float*)d_in[0];
    const float* tkv = (const float*)d_in[1];
    const float* tkh = (const float*)d_in[2];
    const float* tvv = (const float*)d_in[3];
    const float* tvh = (const float*)d_in[4];
    float* o = (float*)d_out;
    attn_super<<<dim3(64 * H_), dim3(256), 0, stream>>>(x, tkv, tkh, tvv, tvh, o);
}

// Round 3
// 96.285 us; speedup vs baseline: 1.2686x; 1.2179x over previous
//
#include <hip/hip_runtime.h>

typedef float  f4v   __attribute__((ext_vector_type(4)));
typedef float  f32x4 __attribute__((ext_vector_type(4)));
typedef short  s8v   __attribute__((ext_vector_type(8)));
typedef short  s4v   __attribute__((ext_vector_type(4)));
typedef __bf16 bf16x8 __attribute__((ext_vector_type(8)));

#define N_   197
#define H_   12
#define CIN  3072
#define COUT 1024
#define PJ   292   // padded row stride for Vt/Pm (146 dwords % 32 = 18 -> conflict-free)

__device__ __forceinline__ unsigned short f2bf(float f) {
    unsigned u = __float_as_uint(f);
    u += 0x7FFFu + ((u >> 16) & 1u);
    return (unsigned short)(u >> 16);
}
__device__ __forceinline__ float bf2f(unsigned short s) {
    return __uint_as_float(((unsigned)s) << 16);
}
__device__ __forceinline__ f32x4 mfma_bf16(s8v a, s8v b, f32x4 c) {
    return __builtin_amdgcn_mfma_f32_16x16x32_bf16(
        __builtin_bit_cast(bf16x8, a), __builtin_bit_cast(bf16x8, b), c, 0, 0, 0);
}

// One block per (b,h), 1024 threads = 16 waves = 4 groups x 4 sub-waves.
// Group g owns q-tiles {g, g+4, g+8, g+12} (one per round); its 4 sub-waves split
// each tile: QK ct-tiles by (ct mod 4), bias/exp likewise, bins by thread, PV by nt.
// LDS: Kl[272][72] bf16 (0..196 K, 208..237 tk_v, 240..269 tk_h, rest 0)
//      Vt[64][PJ]  bf16 (j 0..196 V, 208..237 tv_v, 240..269 tv_h, 272..291 zeroed)
//      Pm[4][16][PJ] bf16 per-group P panel (0..207 P, 208..239 wv, 240..271 wh, 272..287 0)
//      qt[4][16][66] f32 (cols 0..31 q.tk_v, 32..63 q.tk_h)
//      rsP[4][64] f32 row-sum partials [group][s*16+row]
__launch_bounds__(1024, 1)
__global__ void attn_super(const float* __restrict__ x,
                           const float* __restrict__ tkv,
                           const float* __restrict__ tkh,
                           const float* __restrict__ tvv,
                           const float* __restrict__ tvh,
                           float* __restrict__ out) {
    __shared__ __align__(16) unsigned short Kl[272 * 72];
    __shared__ __align__(16) unsigned short Vt[64 * PJ];
    __shared__ __align__(16) unsigned short Pm[4][16 * PJ];
    __shared__ float qt[4][16 * 66];
    __shared__ float rsP[4][64];

    const int bid = blockIdx.x;
    const int b = bid / H_, h = bid % H_;
    const int tid = threadIdx.x;
    const int l  = tid & 63;
    const int lg = (l >> 4);   // 16-lane group within wave
    const int ln = l & 15;
    const int g  = tid >> 8;          // group 0..3
    const int s  = (tid >> 6) & 3;    // sub-wave 0..3

    const float* xb = x + (size_t)b * N_ * CIN;

    // ---- zero-pad output channels [768,1024) (done by h<4 blocks) ----
    if (h < 4) {
        float* oz = out + (size_t)b * N_ * COUT + 768 + h * 64;
        for (int idx = tid; idx < N_ * 16; idx += 1024) {
            int row = idx >> 4, c4 = idx & 15;
            f4v z = {0.f, 0.f, 0.f, 0.f};
            *(f4v*)(oz + (size_t)row * COUT + c4 * 4) = z;
        }
    }

    // ---- stage K_ext (row-major, stride 72 shorts) ----
    for (int idx = tid; idx < 272 * 16; idx += 1024) {
        int row = idx >> 4, c4 = idx & 15;
        int d0 = c4 * 4;
        f4v v = {0.f, 0.f, 0.f, 0.f};
        if (row < N_)                       v = *(const f4v*)(xb + (size_t)row * CIN + 768 + h * 64 + d0);
        else if (row >= 208 && row < 238)   v = *(const f4v*)(tkv + (row - 208) * 64 + d0);
        else if (row >= 240 && row < 270)   v = *(const f4v*)(tkh + (row - 240) * 64 + d0);
        s4v pk;
        pk[0] = (short)f2bf(v[0]); pk[1] = (short)f2bf(v[1]);
        pk[2] = (short)f2bf(v[2]); pk[3] = (short)f2bf(v[3]);
        *(s4v*)(&Kl[row * 72 + d0]) = pk;
    }
    // ---- stage Vt (transposed, j consecutive across lanes) ----
    for (int idx = tid; idx < 288 * 16; idx += 1024) {
        int j = idx % 288, ch = idx / 288;
        int d0 = ch * 4;
        f4v v = {0.f, 0.f, 0.f, 0.f};
        if (j < N_)                         v = *(const f4v*)(xb + (size_t)j * CIN + 1536 + h * 64 + d0);
        else if (j >= 208 && j < 238)       v = *(const f4v*)(tvv + (j - 208) * 64 + d0);
        else if (j >= 240 && j < 270)       v = *(const f4v*)(tvh + (j - 240) * 64 + d0);
        #pragma unroll
        for (int e = 0; e < 4; ++e)
            Vt[(d0 + e) * PJ + j] = f2bf(v[e]);
    }
    // ---- zero Pm tail cols [272,292) once (never written later) ----
    for (int idx = tid; idx < 4 * 16 * 5; idx += 1024) {
        int gq = idx / 80, rem = idx % 80;
        int row = rem / 5, cg = rem % 5;
        s4v z = {0, 0, 0, 0};
        *(s4v*)(&Pm[gq][row * PJ + 272 + cg * 4]) = z;
    }
    __syncthreads();

    for (int rd = 0; rd < 4; ++rd) {
        const int q0 = g + rd * 4;
        const bool act = (q0 < 13);
        const int qb = q0 * 16;

        // ---- phase 1: Q frag + all QK/table MFMAs (ct = s + 4k) ----
        f32x4 accm[4];
        if (act) {
            int qrow = qb + ln; if (qrow > 196) qrow = 196;
            const float* qp = xb + (size_t)qrow * CIN + h * 64;
            s8v aq[2];
            #pragma unroll
            for (int s2 = 0; s2 < 2; ++s2) {
                f4v q1 = *(const f4v*)(qp + s2 * 32 + lg * 8);
                f4v q2 = *(const f4v*)(qp + s2 * 32 + lg * 8 + 4);
                #pragma unroll
                for (int e = 0; e < 4; ++e) {
                    aq[s2][e]     = (short)f2bf(q1[e] * 0.125f);
                    aq[s2][e + 4] = (short)f2bf(q2[e] * 0.125f);
                }
            }
            #pragma unroll
            for (int k = 0; k < 5; ++k) {
                int ct = s + k * 4;
                if (ct < 17) {
                    f32x4 acc = {0.f, 0.f, 0.f, 0.f};
                    #pragma unroll
                    for (int s2 = 0; s2 < 2; ++s2) {
                        const s8v bk = *(const s8v*)(&Kl[(ct * 16 + ln) * 72 + s2 * 32 + lg * 8]);
                        acc = mfma_bf16(aq[s2], bk, acc);
                    }
                    if (ct >= 13) {
                        int cc = (ct - 13) * 16 + ln;
                        #pragma unroll
                        for (int r = 0; r < 4; ++r)
                            qt[g][(lg * 4 + r) * 66 + cc] = acc[r];
                    } else if (k < 4) {
                        accm[k] = acc;
                    }
                }
            }
        }
        __syncthreads();   // qt complete

        // ---- phase 2: bias + exp + write P main cols + row-sum partials ----
        if (act) {
            int ri[4], ci[4];
            #pragma unroll
            for (int r = 0; r < 4; ++r) {
                int i = qb + lg * 4 + r;
                int im1 = i - 1; if (im1 < 0) im1 = 0;
                ri[r] = im1 / 14; ci[r] = im1 - ri[r] * 14;
            }
            float rsp[4] = {0.f, 0.f, 0.f, 0.f};
            #pragma unroll
            for (int k = 0; k < 4; ++k) {
                int ct = s + k * 4;
                if (ct < 13) {
                    f32x4 acc = accm[k];
                    int jj = ct * 16 + ln;
                    int mj = (jj - 1) / 14;
                    int cj = (jj - 1) - mj * 14;
                    bool jv = (jj < N_);
                    #pragma unroll
                    for (int r = 0; r < 4; ++r) {
                        int i = qb + lg * 4 + r;
                        bool z = (i == 0) || (jj == 0);
                        int t = z ? 0 : (mj - ri[r] + 15);
                        int u = z ? 32 : (cj - ci[r] + 15 + 32);
                        float bias = qt[g][(lg * 4 + r) * 66 + t] + qt[g][(lg * 4 + r) * 66 + u];
                        float p = __expf(acc[r] + bias);
                        p = jv ? p : 0.f;
                        rsp[r] += p;
                        Pm[g][(lg * 4 + r) * PJ + jj] = f2bf(p);
                    }
                }
            }
            #pragma unroll
            for (int r = 0; r < 4; ++r) {
                float v = rsp[r];
                v += __shfl_xor(v, 1); v += __shfl_xor(v, 2);
                v += __shfl_xor(v, 4); v += __shfl_xor(v, 8);
                rsp[r] = v;
            }
            if (ln == 0) {
                #pragma unroll
                for (int r = 0; r < 4; ++r)
                    rsP[g][s * 16 + lg * 4 + r] = rsp[r];
            }
        }
        __syncthreads();   // P main cols + rs partials complete

        // ---- phase 3: row-sum totals + bin slots (computed-or-zero, all 64/row) ----
        float rst[4];
        if (act) {
            #pragma unroll
            for (int r = 0; r < 4; ++r) {
                int row = lg * 4 + r;
                rst[r] = rsP[g][row] + rsP[g][16 + row] + rsP[g][32 + row] + rsP[g][48 + row];
            }
            int th = tid & 255;
            int table = th >> 7;            // 0: wv (runs), 1: wh (strided cols)
            int row = (th >> 3) & 15;
            int i = qb + row;
            int im1 = i - 1; if (im1 < 0) im1 = 0;
            int rit = im1 / 14, cit = im1 - rit * 14;
            int base = table ? cit : rit;
            bool row0 = (i == 0);
            const unsigned short* pr = &Pm[g][row * PJ];
            float rsrow = rsP[g][row] + rsP[g][16 + row] + rsP[g][32 + row] + rsP[g][48 + row];
            #pragma unroll
            for (int k = 0; k < 4; ++k) {
                int t = (th & 7) + k * 8;
                float val = 0.f;
                if (row0) {
                    val = (t == 0) ? rsrow : 0.f;
                } else if (t == 0) {
                    val = bf2f(pr[0]);
                } else {
                    int m = t - 15 + base;
                    if (m >= 0 && m < 14) {
                        float sum = 0.f;
                        if (table == 0) {
                            #pragma unroll
                            for (int e = 0; e < 14; ++e) sum += bf2f(pr[1 + 14 * m + e]);
                        } else {
                            #pragma unroll
                            for (int e = 0; e < 14; ++e) sum += bf2f(pr[1 + 14 * e + m]);
                        }
                        val = sum;
                    }
                }
                Pm[g][row * PJ + 208 + table * 32 + t] = f2bf(val);
            }
        }
        __syncthreads();   // bins complete

        // ---- phase 4: PV for nt = s (one 16-wide d-tile) + store ----
        if (act) {
            const int nt = s;
            f32x4 oacc = {0.f, 0.f, 0.f, 0.f};
            for (int kt = 0; kt < 9; ++kt) {
                const s8v ap = *(const s8v*)(&Pm[g][ln * PJ + kt * 32 + lg * 8]);
                const s8v bv = *(const s8v*)(&Vt[(nt * 16 + ln) * PJ + kt * 32 + lg * 8]);
                oacc = mfma_bf16(ap, bv, oacc);
            }
            #pragma unroll
            for (int r = 0; r < 4; ++r) {
                int n = qb + lg * 4 + r;
                if (n < N_) {
                    out[((size_t)b * N_ + n) * COUT + h * 64 + nt * 16 + ln] = oacc[r] / rst[r];
                }
            }
        }
        // no barrier here: next round's post-phase-1 barrier separates
        // these Pm/Vt reads from the next Pm writes (phase 2).
    }
}

extern "C" void kernel_launch(void* const* d_in, const int* in_sizes, int n_in,
                              void* d_out, int out_size, void* d_ws, size_t ws_size,
                              hipStream_t stream) {
    const float* x   = (const float*)d_in[0];
    const float* tkv = (const float*)d_in[1];
    const float* tkh = (const float*)d_in[2];
    const float* tvv = (const float*)d_in[3];
    const float* tvh = (const float*)d_in[4];
    float* o = (float*)d_out;
    attn_super<<<dim3(64 * H_), dim3(1024), 0, stream>>>(x, tkv, tkh, tvv, tvh, o);
}

// Round 6
// 76.797 us; speedup vs baseline: 1.5905x; 1.2538x over previous
//
#include <hip/hip_runtime.h>

typedef float  f4v   __attribute__((ext_vector_type(4)));
typedef float  f32x4 __attribute__((ext_vector_type(4)));
typedef short  s8v   __attribute__((ext_vector_type(8)));
typedef short  s4v   __attribute__((ext_vector_type(4)));
typedef __bf16 bf16x8 __attribute__((ext_vector_type(8)));

#define N_   197
#define H_   12
#define CIN  3072
#define COUT 1024
#define VSTR 296   // Vt row stride (shorts)
#define ASTR 72    // arena row stride (shorts)

// Compiler memory fence (ordering belt; volatile arena stores are braces).
#define MEMBAR() asm volatile("" ::: "memory")

__device__ __forceinline__ unsigned short f2bf(float f) {
    unsigned u = __float_as_uint(f);
    u += 0x7FFFu + ((u >> 16) & 1u);
    return (unsigned short)(u >> 16);
}
__device__ __forceinline__ float bf2f(unsigned short s) {
    return __uint_as_float(((unsigned)s) << 16);
}
__device__ __forceinline__ f32x4 mfma_bf16(s8v a, s8v b, f32x4 c) {
    return __builtin_amdgcn_mfma_f32_16x16x32_bf16(
        __builtin_bit_cast(bf16x8, a), __builtin_bit_cast(bf16x8, b), c, 0, 0, 0);
}

// One block per (b,h), 1024 threads = 16 waves. Wave w (<13) owns q-tile w,
// fully independently (ONE barrier after staging, none after).
// Swapped QK^T: S C-frag holds S[k=ct*16+4lg+r][q=ln] -> softmax in registers.
// Bins (rel-pos value einsum) via indicator MFMA: wv = P*Sv, wh = P*Sh.
__launch_bounds__(1024, 4)
__global__ void attn_super(const float* __restrict__ x,
                           const float* __restrict__ tkv,
                           const float* __restrict__ tkh,
                           const float* __restrict__ tvv,
                           const float* __restrict__ tvh,
                           float* __restrict__ out) {
    __shared__ __align__(16) unsigned short Kl[272 * 72];
    __shared__ __align__(16) unsigned short Vt[64 * VSTR];
    __shared__ __align__(16) unsigned short AR[16][16 * ASTR];
    __shared__ __align__(16) unsigned short INDv[16 * 224];
    __shared__ __align__(16) unsigned short INDh[16 * 224];

    const int bid = blockIdx.x;
    const int b = bid / H_, h = bid % H_;
    const int tid = threadIdx.x;
    const int w  = tid >> 6;       // wave 0..15
    const int l  = tid & 63;
    const int lg = l >> 4;         // 16-lane group
    const int ln = l & 15;

    const float* xb = x + (size_t)b * N_ * CIN;

    // ---- zero-pad output channels [768,1024) (h<4 blocks) ----
    if (h < 4) {
        float* oz = out + (size_t)b * N_ * COUT + 768 + h * 64;
        for (int idx = tid; idx < N_ * 16; idx += 1024) {
            int row = idx >> 4, c4 = idx & 15;
            f4v z = {0.f, 0.f, 0.f, 0.f};
            *(f4v*)(oz + (size_t)row * COUT + c4 * 4) = z;
        }
    }
    // ---- stage K_ext ----
    for (int idx = tid; idx < 272 * 16; idx += 1024) {
        int row = idx >> 4, d0 = (idx & 15) * 4;
        f4v v = {0.f, 0.f, 0.f, 0.f};
        if (row < N_)                       v = *(const f4v*)(xb + (size_t)row * CIN + 768 + h * 64 + d0);
        else if (row >= 208 && row < 238)   v = *(const f4v*)(tkv + (row - 208) * 64 + d0);
        else if (row >= 240 && row < 270)   v = *(const f4v*)(tkh + (row - 240) * 64 + d0);
        s4v pk;
        pk[0] = (short)f2bf(v[0]); pk[1] = (short)f2bf(v[1]);
        pk[2] = (short)f2bf(v[2]); pk[3] = (short)f2bf(v[3]);
        *(s4v*)(&Kl[row * 72 + d0]) = pk;
    }
    // ---- stage Vt (transposed; tables at cols 224/256) ----
    for (int idx = tid; idx < 288 * 16; idx += 1024) {
        int j = idx % 288, d0 = (idx / 288) * 4;
        f4v v = {0.f, 0.f, 0.f, 0.f};
        if (j < N_)                         v = *(const f4v*)(xb + (size_t)j * CIN + 1536 + h * 64 + d0);
        else if (j >= 224 && j < 254)       v = *(const f4v*)(tvv + (j - 224) * 64 + d0);
        else if (j >= 256 && j < 286)       v = *(const f4v*)(tvh + (j - 256) * 64 + d0);
        #pragma unroll
        for (int e = 0; e < 4; ++e)
            Vt[(d0 + e) * VSTR + j] = f2bf(v[e]);
    }
    // ---- build indicator tables ----
    for (int idx = tid; idx < 16 * 224; idx += 1024) {
        int m = idx / 224, k = idx % 224;
        int km1 = k - 1;
        bool kv = (k >= 1 && k <= 196);
        INDv[idx] = (kv && (km1 / 14) == m) ? (unsigned short)0x3F80 : (unsigned short)0;
        INDh[idx] = (kv && (km1 % 14) == m) ? (unsigned short)0x3F80 : (unsigned short)0;
    }
    __syncthreads();

    if (w >= 13) return;

    const int tile = w, qb = tile * 16;
    const unsigned short* ar = &AR[w][0];           // reads (plain)
    volatile unsigned short* arv = &AR[w][0];       // writes (volatile, same elem type)

    // per-lane bias constants for q-row i = qb + ln
    const int iL  = qb + ln;
    const int im1 = (iL > 0) ? iL - 1 : 0;
    const int rit = im1 / 14;
    const int cit = im1 - rit * 14;

    // ---- Q B-frags (pre-scaled 1/8) ----
    int qrow = qb + ln; if (qrow > 196) qrow = 196;
    const float* qp = xb + (size_t)qrow * CIN + h * 64;
    s8v aq[2];
    #pragma unroll
    for (int s2 = 0; s2 < 2; ++s2) {
        f4v q1 = *(const f4v*)(qp + s2 * 32 + lg * 8);
        f4v q2 = *(const f4v*)(qp + s2 * 32 + lg * 8 + 4);
        #pragma unroll
        for (int e = 0; e < 4; ++e) {
            aq[s2][e]     = (short)f2bf(q1[e] * 0.125f);
            aq[s2][e + 4] = (short)f2bf(q2[e] * 0.125f);
        }
    }
    // ---- swapped QK^T: S[ct] holds S[k=ct*16+4lg+r][q=ln] ----
    f32x4 S[13];
    #pragma unroll
    for (int ct = 0; ct < 13; ++ct) {
        f32x4 acc = {0.f, 0.f, 0.f, 0.f};
        #pragma unroll
        for (int s2 = 0; s2 < 2; ++s2) {
            const s8v bk = *(const s8v*)(&Kl[(ct * 16 + ln) * 72 + s2 * 32 + lg * 8]);
            acc = mfma_bf16(bk, aq[s2], acc);
        }
        S[ct] = acc;
    }
    // ---- table tiles -> qt (arena cols 0..63, row = q = ln) ----
    #pragma unroll
    for (int tt = 0; tt < 4; ++tt) {
        f32x4 acc = {0.f, 0.f, 0.f, 0.f};
        #pragma unroll
        for (int s2 = 0; s2 < 2; ++s2) {
            const s8v bk = *(const s8v*)(&Kl[((13 + tt) * 16 + ln) * 72 + s2 * 32 + lg * 8]);
            acc = mfma_bf16(bk, aq[s2], acc);
        }
        #pragma unroll
        for (int r = 0; r < 4; ++r)
            arv[ln * ASTR + tt * 16 + 4 * lg + r] = f2bf(acc[r]);
    }
    MEMBAR();
    // row i==0 fix: make general gather formula read qtv[0]/qth[0] everywhere
    if (tile == 0) {
        unsigned short c0  = ar[0];
        unsigned short c32 = ar[32];
        if (l >= 15 && l <= 28) arv[l] = c0;
        if (l >= 47 && l <= 60) arv[l] = c32;
    }
    MEMBAR();
    // ---- bias + exp + row-sum (all in registers) ----
    float rs4[4] = {0.f, 0.f, 0.f, 0.f};
    #pragma unroll
    for (int ct = 0; ct < 13; ++ct) {
        int mj[4], cj[4];
        if (ct == 0) {
            #pragma unroll
            for (int r = 0; r < 4; ++r) {
                int km1 = 4 * lg + r - 1;
                int w14 = (km1 >= 14) ? 1 : 0;
                mj[r] = w14; cj[r] = km1 - 14 * w14;
            }
        } else {
            unsigned e0 = (unsigned)(ct * 16 - 1 + 4 * lg);
            unsigned m0 = e0 / 14u;
            unsigned c0 = e0 - m0 * 14u;
            #pragma unroll
            for (int r = 0; r < 4; ++r) {
                unsigned c = c0 + (unsigned)r;
                int wr = (c >= 14u) ? 1 : 0;
                mj[r] = (int)m0 + wr; cj[r] = (int)c - 14 * wr;
            }
        }
        #pragma unroll
        for (int r = 0; r < 4; ++r) {
            int t = mj[r] - rit + 15;
            int u = cj[r] - cit + 47;
            if (ct == 0 && r == 0) {            // k==0 column -> table row 0
                bool z = (lg == 0);
                t = z ? 0 : t;
                u = z ? 32 : u;
            }
            float bias = bf2f(ar[ln * ASTR + t]) + bf2f(ar[ln * ASTR + u]);
            float p = __expf(S[ct][r] + bias);
            if (ct == 12) { if (4 * lg + r > 4) p = 0.f; }   // k>196 invalid
            S[ct][r] = p;
            rs4[r] += p;
        }
    }
    float rs = (rs4[0] + rs4[1]) + (rs4[2] + rs4[3]);
    rs += __shfl_xor(rs, 16);
    rs += __shfl_xor(rs, 32);
    float p00 = S[0][0];
    float rsq[4], p0q[4];
    #pragma unroll
    for (int r = 0; r < 4; ++r) {
        rsq[r] = __shfl(rs,  4 * lg + r);
        p0q[r] = __shfl(p00, 4 * lg + r);
    }
    // per-output-row bin shift constants (row q = 4lg + r)
    int ritq[4], citq[4];
    #pragma unroll
    for (int r = 0; r < 4; ++r) {
        int qr2 = qb + 4 * lg + r;
        int im  = (qr2 > 0) ? qr2 - 1 : 0;
        ritq[r] = im / 14;
        citq[r] = im - ritq[r] * 14;
    }
    // ---- PV + bins via sliding 64-col arena window ----
    f32x4 oacc[4];
    #pragma unroll
    for (int nt = 0; nt < 4; ++nt) { f32x4 z = {0.f,0.f,0.f,0.f}; oacc[nt] = z; }
    f32x4 cwv = {0.f,0.f,0.f,0.f}, cwh = {0.f,0.f,0.f,0.f};

    #pragma unroll
    for (int win = 0; win < 3; ++win) {         // k 0..63, 64..127, 128..191
        MEMBAR();
        #pragma unroll
        for (int cc = 0; cc < 4; ++cc) {
            int ct = win * 4 + cc;
            #pragma unroll
            for (int r = 0; r < 4; ++r)
                arv[ln * ASTR + cc * 16 + 4 * lg + r] = f2bf(S[ct][r]);
        }
        MEMBAR();
        #pragma unroll
        for (int kk = 0; kk < 2; ++kk) {
            int kt = win * 2 + kk;
            const s8v ap = *(const s8v*)(&ar[ln * ASTR + kk * 32 + lg * 8]);
            #pragma unroll
            for (int nt = 0; nt < 4; ++nt) {
                const s8v bv = *(const s8v*)(&Vt[(nt * 16 + ln) * VSTR + kt * 32 + lg * 8]);
                oacc[nt] = mfma_bf16(ap, bv, oacc[nt]);
            }
            const s8v bi = *(const s8v*)(&INDv[ln * 224 + kt * 32 + lg * 8]);
            cwv = mfma_bf16(ap, bi, cwv);
            const s8v bh = *(const s8v*)(&INDh[ln * 224 + kt * 32 + lg * 8]);
            cwh = mfma_bf16(ap, bh, cwh);
        }
    }
    { // window 3: k 192..255  (P ct12 | zeros | wv bins)
        MEMBAR();
        #pragma unroll
        for (int r = 0; r < 4; ++r)
            arv[ln * ASTR + 4 * lg + r] = f2bf(S[12][r]);
        #pragma unroll
        for (int r = 0; r < 4; ++r)
            arv[ln * ASTR + 16 + 4 * lg + r] = 0;
        #pragma unroll
        for (int z = 0; z < 8; ++z)
            arv[ln * ASTR + 32 + lg * 8 + z] = 0;
        MEMBAR();
        { // kt6 (k 192..223)
            const s8v ap = *(const s8v*)(&ar[ln * ASTR + lg * 8]);
            #pragma unroll
            for (int nt = 0; nt < 4; ++nt) {
                const s8v bv = *(const s8v*)(&Vt[(nt * 16 + ln) * VSTR + 192 + lg * 8]);
                oacc[nt] = mfma_bf16(ap, bv, oacc[nt]);
            }
            const s8v bi = *(const s8v*)(&INDv[ln * 224 + 192 + lg * 8]);
            cwv = mfma_bf16(ap, bi, cwv);
            const s8v bh = *(const s8v*)(&INDh[ln * 224 + 192 + lg * 8]);
            cwh = mfma_bf16(ap, bh, cwh);
        }
        MEMBAR();
        // scatter wv bins: C_wv[q=4lg+r][m=ln] -> col 32 + (ln - ritq + 15)
        #pragma unroll
        for (int r = 0; r < 4; ++r) {
            int q = 4 * lg + r;
            bool isRow0 = (tile == 0) && (q == 0);
            if (ln <= 13 && !isRow0)
                arv[q * ASTR + 47 + ln - ritq[r]] = f2bf(cwv[r]);
            if (ln == 15)
                arv[q * ASTR + 32] = f2bf(isRow0 ? rsq[r] : p0q[r]);
        }
        MEMBAR();
        { // kt7 (k 224..255 = tv_v bins)
            const s8v ap = *(const s8v*)(&ar[ln * ASTR + 32 + lg * 8]);
            #pragma unroll
            for (int nt = 0; nt < 4; ++nt) {
                const s8v bv = *(const s8v*)(&Vt[(nt * 16 + ln) * VSTR + 224 + lg * 8]);
                oacc[nt] = mfma_bf16(ap, bv, oacc[nt]);
            }
        }
    }
    { // window 4: k 256..287 (wh bins)
        MEMBAR();
        #pragma unroll
        for (int z = 0; z < 8; ++z)
            arv[ln * ASTR + lg * 8 + z] = 0;
        MEMBAR();
        #pragma unroll
        for (int r = 0; r < 4; ++r) {
            int q = 4 * lg + r;
            bool isRow0 = (tile == 0) && (q == 0);
            if (ln <= 13 && !isRow0)
                arv[q * ASTR + 15 + ln - citq[r]] = f2bf(cwh[r]);
            if (ln == 15)
                arv[q * ASTR + 0] = f2bf(isRow0 ? rsq[r] : p0q[r]);
        }
        MEMBAR();
        { // kt8
            const s8v ap = *(const s8v*)(&ar[ln * ASTR + lg * 8]);
            #pragma unroll
            for (int nt = 0; nt < 4; ++nt) {
                const s8v bv = *(const s8v*)(&Vt[(nt * 16 + ln) * VSTR + 256 + lg * 8]);
                oacc[nt] = mfma_bf16(ap, bv, oacc[nt]);
            }
        }
    }
    // ---- normalize + store (C row = q = 4lg+r, col = d = nt*16+ln) ----
    #pragma unroll
    for (int r = 0; r < 4; ++r) {
        int n = qb + 4 * lg + r;
        if (n < N_) {
            float sc = 1.0f / rsq[r];
            float* orow = out + ((size_t)b * N_ + n) * COUT + h * 64;
            #pragma unroll
            for (int nt = 0; nt < 4; ++nt)
                orow[nt * 16 + ln] = oacc[nt][r] * sc;
        }
    }
}

extern "C" void kernel_launch(void* const* d_in, const int* in_sizes, int n_in,
                              void* d_out, int out_size, void* d_ws, size_t ws_size,
                              hipStream_t stream) {
    const float* x   = (const float*)d_in[0];
    const float* tkv = (const float*)d_in[1];
    const float* tkh = (const float*)d_in[2];
    const float* tvv = (const float*)d_in[3];
    const float* tvh = (const float*)d_in[4];
    float* o = (float*)d_out;
    attn_super<<<dim3(64 * H_), dim3(1024), 0, stream>>>(x, tkv, tkh, tvv, tvh, o);
}

// Round 7
// 75.338 us; speedup vs baseline: 1.6214x; 1.0194x over previous
//
#include <hip/hip_runtime.h>

typedef float  f4v   __attribute__((ext_vector_type(4)));
typedef float  f32x4 __attribute__((ext_vector_type(4)));
typedef short  s8v   __attribute__((ext_vector_type(8)));
typedef short  s4v   __attribute__((ext_vector_type(4)));
typedef __bf16 bf16x8 __attribute__((ext_vector_type(8)));

#define N_   197
#define H_   12
#define CIN  3072
#define COUT 1024
#define VSTR 296   // Vt row stride (shorts)
#define ASTR 72    // arena row stride (shorts)

#define MEMBAR() asm volatile("" ::: "memory")

__device__ __forceinline__ unsigned short f2bf(float f) {
    unsigned u = __float_as_uint(f);
    u += 0x7FFFu + ((u >> 16) & 1u);
    return (unsigned short)(u >> 16);
}
__device__ __forceinline__ float bf2f(unsigned short s) {
    return __uint_as_float(((unsigned)s) << 16);
}
__device__ __forceinline__ f32x4 mfma_bf16(s8v a, s8v b, f32x4 c) {
    return __builtin_amdgcn_mfma_f32_16x16x32_bf16(
        __builtin_bit_cast(bf16x8, a), __builtin_bit_cast(bf16x8, b), c, 0, 0, 0);
}
// vectorized volatile arena store (same short element family as R6's proven path)
__device__ __forceinline__ void st4f(volatile unsigned short* p, float a, float b, float c, float d) {
    s4v v;
    v[0] = (short)f2bf(a); v[1] = (short)f2bf(b);
    v[2] = (short)f2bf(c); v[3] = (short)f2bf(d);
    *(volatile s4v*)p = v;
}
__device__ __forceinline__ void st4z(volatile unsigned short* p) {
    s4v v = {0, 0, 0, 0};
    *(volatile s4v*)p = v;
}

// One block per (b,h), 1024 threads = 16 waves. Wave w (<13) owns q-tile w.
// Pipeline: prefetch K/V/Q to regs -> write K -> B1 -> QK^T/table (V latency
// hides here) -> write V -> softmax -> B2 -> PV. Two barriers total.
// Swapped QK^T: S C-frag holds S[k=ct*16+4lg+r][q=ln] -> softmax in registers.
// Bins (rel-pos value einsum) via indicator MFMA: wv = P*Sv, wh = P*Sh.
__launch_bounds__(1024, 4)
__global__ void attn_super(const float* __restrict__ x,
                           const float* __restrict__ tkv,
                           const float* __restrict__ tkh,
                           const float* __restrict__ tvv,
                           const float* __restrict__ tvh,
                           float* __restrict__ out) {
    __shared__ __align__(16) unsigned short Kl[272 * 72];
    __shared__ __align__(16) unsigned short Vt[64 * VSTR];
    __shared__ __align__(16) unsigned short AR[16][16 * ASTR];
    __shared__ __align__(16) unsigned short INDv[16 * 224];
    __shared__ __align__(16) unsigned short INDh[16 * 224];

    const int bid = blockIdx.x;
    const int b = bid / H_, h = bid % H_;
    const int tid = threadIdx.x;
    const int w  = tid >> 6;       // wave 0..15
    const int l  = tid & 63;
    const int lg = l >> 4;         // 16-lane group
    const int ln = l & 15;

    const float* xb = x + (size_t)b * N_ * CIN;

    // ---- zero-pad output channels [768,1024) (h<4 blocks): issue early ----
    if (h < 4) {
        float* oz = out + (size_t)b * N_ * COUT + 768 + h * 64;
        for (int idx = tid; idx < N_ * 16; idx += 1024) {
            int row = idx >> 4, c4 = idx & 15;
            f4v z = {0.f, 0.f, 0.f, 0.f};
            *(f4v*)(oz + (size_t)row * COUT + c4 * 4) = z;
        }
    }

    // ---- PROLOGUE: issue ALL global loads (K, then Q, then V) ----
    f4v kr[5];
    #pragma unroll
    for (int it = 0; it < 5; ++it) {
        int idx = it * 1024 + tid;
        bool a5 = (it < 4) || (tid < 256);       // 272*16 = 4352
        int row = idx >> 4, d0 = (idx & 15) * 4;
        f4v v = {0.f, 0.f, 0.f, 0.f};
        if (a5) {
            if (row < N_)                     v = *(const f4v*)(xb + (size_t)row * CIN + 768 + h * 64 + d0);
            else if (row >= 208 && row < 238) v = *(const f4v*)(tkv + (row - 208) * 64 + d0);
            else if (row >= 240 && row < 270) v = *(const f4v*)(tkh + (row - 240) * 64 + d0);
        }
        kr[it] = v;
    }
    f4v q1[2], q2[2];
    if (w < 13) {
        int qrow = w * 16 + ln; if (qrow > 196) qrow = 196;
        const float* qp = xb + (size_t)qrow * CIN + h * 64;
        #pragma unroll
        for (int s2 = 0; s2 < 2; ++s2) {
            q1[s2] = *(const f4v*)(qp + s2 * 32 + lg * 8);
            q2[s2] = *(const f4v*)(qp + s2 * 32 + lg * 8 + 4);
        }
    }
    f4v vr[5];
    #pragma unroll
    for (int it = 0; it < 5; ++it) {
        int idx = it * 1024 + tid;
        bool a5 = (it < 4) || (tid < 512);       // 288*16 = 4608
        int j = idx % 288, d0 = (idx / 288) * 4;
        f4v v = {0.f, 0.f, 0.f, 0.f};
        if (a5) {
            if (j < N_)                     v = *(const f4v*)(xb + (size_t)j * CIN + 1536 + h * 64 + d0);
            else if (j >= 224 && j < 254)   v = *(const f4v*)(tvv + (j - 224) * 64 + d0);
            else if (j >= 256 && j < 286)   v = *(const f4v*)(tvh + (j - 256) * 64 + d0);
        }
        vr[it] = v;
    }

    // ---- write K -> LDS (waits only on K loads) ----
    #pragma unroll
    for (int it = 0; it < 5; ++it) {
        int idx = it * 1024 + tid;
        bool a5 = (it < 4) || (tid < 256);
        if (a5) {
            int row = idx >> 4, d0 = (idx & 15) * 4;
            f4v v = kr[it];
            s4v pk;
            pk[0] = (short)f2bf(v[0]); pk[1] = (short)f2bf(v[1]);
            pk[2] = (short)f2bf(v[2]); pk[3] = (short)f2bf(v[3]);
            *(s4v*)(&Kl[row * 72 + d0]) = pk;
        }
    }
    // ---- build indicator tables (VALU-only) ----
    for (int idx = tid; idx < 16 * 224; idx += 1024) {
        int m = idx / 224, k = idx % 224;
        int km1 = k - 1;
        bool kv = (k >= 1 && k <= 196);
        INDv[idx] = (kv && (km1 / 14) == m) ? (unsigned short)0x3F80 : (unsigned short)0;
        INDh[idx] = (kv && (km1 % 14) == m) ? (unsigned short)0x3F80 : (unsigned short)0;
    }
    __syncthreads();   // B1: Kl + IND ready

    const int tile = w, qb = tile * 16;
    const unsigned short* ar = &AR[w][0];
    volatile unsigned short* arv = &AR[w][0];

    f32x4 S[13];
    if (w < 13) {
        // Q frags from prefetched regs (pre-scaled 1/8)
        s8v aq[2];
        #pragma unroll
        for (int s2 = 0; s2 < 2; ++s2) {
            #pragma unroll
            for (int e = 0; e < 4; ++e) {
                aq[s2][e]     = (short)f2bf(q1[s2][e] * 0.125f);
                aq[s2][e + 4] = (short)f2bf(q2[s2][e] * 0.125f);
            }
        }
        // swapped QK^T
        #pragma unroll
        for (int ct = 0; ct < 13; ++ct) {
            f32x4 acc = {0.f, 0.f, 0.f, 0.f};
            #pragma unroll
            for (int s2 = 0; s2 < 2; ++s2) {
                const s8v bk = *(const s8v*)(&Kl[(ct * 16 + ln) * 72 + s2 * 32 + lg * 8]);
                acc = mfma_bf16(bk, aq[s2], acc);
            }
            S[ct] = acc;
        }
        // table tiles -> qt (arena cols 0..63, row = q = ln)
        #pragma unroll
        for (int tt = 0; tt < 4; ++tt) {
            f32x4 acc = {0.f, 0.f, 0.f, 0.f};
            #pragma unroll
            for (int s2 = 0; s2 < 2; ++s2) {
                const s8v bk = *(const s8v*)(&Kl[((13 + tt) * 16 + ln) * 72 + s2 * 32 + lg * 8]);
                acc = mfma_bf16(bk, aq[s2], acc);
            }
            st4f(&arv[ln * ASTR + tt * 16 + 4 * lg], acc[0], acc[1], acc[2], acc[3]);
        }
    }
    // ---- write V -> LDS (ALL waves; V-load latency hid under QK for w<13) ----
    #pragma unroll
    for (int it = 0; it < 5; ++it) {
        int idx = it * 1024 + tid;
        bool a5 = (it < 4) || (tid < 512);
        if (a5) {
            int j = idx % 288, d0 = (idx / 288) * 4;
            f4v v = vr[it];
            #pragma unroll
            for (int e = 0; e < 4; ++e)
                Vt[(d0 + e) * VSTR + j] = f2bf(v[e]);
        }
    }

    float rsq[4], p0q[4];
    int ritq[4], citq[4];
    if (w < 13) {
        MEMBAR();
        // row i==0 fix: make gather formula read qtv[0]/qth[0] everywhere
        if (tile == 0) {
            unsigned short c0  = ar[0];
            unsigned short c32 = ar[32];
            if (l >= 15 && l <= 28) arv[l] = c0;
            if (l >= 47 && l <= 60) arv[l] = c32;
        }
        MEMBAR();
        // per-lane bias constants for q-row i = qb + ln
        const int iL  = qb + ln;
        const int im1 = (iL > 0) ? iL - 1 : 0;
        const int rit = im1 / 14;
        const int cit = im1 - rit * 14;
        // bias + exp + row-sum (registers)
        float rs4[4] = {0.f, 0.f, 0.f, 0.f};
        #pragma unroll
        for (int ct = 0; ct < 13; ++ct) {
            int mj[4], cj[4];
            if (ct == 0) {
                #pragma unroll
                for (int r = 0; r < 4; ++r) {
                    int km1 = 4 * lg + r - 1;
                    int w14 = (km1 >= 14) ? 1 : 0;
                    mj[r] = w14; cj[r] = km1 - 14 * w14;
                }
            } else {
                unsigned e0 = (unsigned)(ct * 16 - 1 + 4 * lg);
                unsigned m0 = e0 / 14u;
                unsigned c0 = e0 - m0 * 14u;
                #pragma unroll
                for (int r = 0; r < 4; ++r) {
                    unsigned c = c0 + (unsigned)r;
                    int wr = (c >= 14u) ? 1 : 0;
                    mj[r] = (int)m0 + wr; cj[r] = (int)c - 14 * wr;
                }
            }
            #pragma unroll
            for (int r = 0; r < 4; ++r) {
                int t = mj[r] - rit + 15;
                int u = cj[r] - cit + 47;
                if (ct == 0 && r == 0) {            // k==0 column -> table row 0
                    bool z = (lg == 0);
                    t = z ? 0 : t;
                    u = z ? 32 : u;
                }
                float bias = bf2f(ar[ln * ASTR + t]) + bf2f(ar[ln * ASTR + u]);
                float p = __expf(S[ct][r] + bias);
                if (ct == 12) { if (4 * lg + r > 4) p = 0.f; }   // k>196 invalid
                S[ct][r] = p;
                rs4[r] += p;
            }
        }
        float rs = (rs4[0] + rs4[1]) + (rs4[2] + rs4[3]);
        rs += __shfl_xor(rs, 16);
        rs += __shfl_xor(rs, 32);
        float p00 = S[0][0];
        #pragma unroll
        for (int r = 0; r < 4; ++r) {
            rsq[r] = __shfl(rs,  4 * lg + r);
            p0q[r] = __shfl(p00, 4 * lg + r);
        }
        #pragma unroll
        for (int r = 0; r < 4; ++r) {
            int qr2 = qb + 4 * lg + r;
            int im  = (qr2 > 0) ? qr2 - 1 : 0;
            ritq[r] = im / 14;
            citq[r] = im - ritq[r] * 14;
        }
    }
    __syncthreads();   // B2: Vt ready

    if (w >= 13) return;

    // ---- PV + bins via sliding 64-col arena window ----
    f32x4 oacc[4];
    #pragma unroll
    for (int nt = 0; nt < 4; ++nt) { f32x4 z = {0.f,0.f,0.f,0.f}; oacc[nt] = z; }
    f32x4 cwv = {0.f,0.f,0.f,0.f}, cwh = {0.f,0.f,0.f,0.f};

    #pragma unroll
    for (int win = 0; win < 3; ++win) {         // k 0..63, 64..127, 128..191
        MEMBAR();
        #pragma unroll
        for (int cc = 0; cc < 4; ++cc) {
            int ct = win * 4 + cc;
            st4f(&arv[ln * ASTR + cc * 16 + 4 * lg], S[ct][0], S[ct][1], S[ct][2], S[ct][3]);
        }
        MEMBAR();
        #pragma unroll
        for (int kk = 0; kk < 2; ++kk) {
            int kt = win * 2 + kk;
            const s8v ap = *(const s8v*)(&ar[ln * ASTR + kk * 32 + lg * 8]);
            #pragma unroll
            for (int nt = 0; nt < 4; ++nt) {
                const s8v bv = *(const s8v*)(&Vt[(nt * 16 + ln) * VSTR + kt * 32 + lg * 8]);
                oacc[nt] = mfma_bf16(ap, bv, oacc[nt]);
            }
            const s8v bi = *(const s8v*)(&INDv[ln * 224 + kt * 32 + lg * 8]);
            cwv = mfma_bf16(ap, bi, cwv);
            const s8v bh = *(const s8v*)(&INDh[ln * 224 + kt * 32 + lg * 8]);
            cwh = mfma_bf16(ap, bh, cwh);
        }
    }
    { // window 3: k 192..255  (P ct12 | zeros | wv bins)
        MEMBAR();
        st4f(&arv[ln * ASTR + 4 * lg], S[12][0], S[12][1], S[12][2], S[12][3]);
        st4z(&arv[ln * ASTR + 16 + 4 * lg]);
        st4z(&arv[ln * ASTR + 32 + lg * 8]);
        st4z(&arv[ln * ASTR + 36 + lg * 8]);
        MEMBAR();
        { // kt6 (k 192..223)
            const s8v ap = *(const s8v*)(&ar[ln * ASTR + lg * 8]);
            #pragma unroll
            for (int nt = 0; nt < 4; ++nt) {
                const s8v bv = *(const s8v*)(&Vt[(nt * 16 + ln) * VSTR + 192 + lg * 8]);
                oacc[nt] = mfma_bf16(ap, bv, oacc[nt]);
            }
            const s8v bi = *(const s8v*)(&INDv[ln * 224 + 192 + lg * 8]);
            cwv = mfma_bf16(ap, bi, cwv);
            const s8v bh = *(const s8v*)(&INDh[ln * 224 + 192 + lg * 8]);
            cwh = mfma_bf16(ap, bh, cwh);
        }
        MEMBAR();
        // scatter wv bins: C_wv[q=4lg+r][m=ln] -> col 32 + (ln - ritq + 15)
        #pragma unroll
        for (int r = 0; r < 4; ++r) {
            int q = 4 * lg + r;
            bool isRow0 = (tile == 0) && (q == 0);
            if (ln <= 13 && !isRow0)
                arv[q * ASTR + 47 + ln - ritq[r]] = f2bf(cwv[r]);
            if (ln == 15)
                arv[q * ASTR + 32] = f2bf(isRow0 ? rsq[r] : p0q[r]);
        }
        MEMBAR();
        { // kt7 (k 224..255 = tv_v bins)
            const s8v ap = *(const s8v*)(&ar[ln * ASTR + 32 + lg * 8]);
            #pragma unroll
            for (int nt = 0; nt < 4; ++nt) {
                const s8v bv = *(const s8v*)(&Vt[(nt * 16 + ln) * VSTR + 224 + lg * 8]);
                oacc[nt] = mfma_bf16(ap, bv, oacc[nt]);
            }
        }
    }
    { // window 4: k 256..287 (wh bins)
        MEMBAR();
        st4z(&arv[ln * ASTR + lg * 8]);
        st4z(&arv[ln * ASTR + 4 + lg * 8]);
        MEMBAR();
        #pragma unroll
        for (int r = 0; r < 4; ++r) {
            int q = 4 * lg + r;
            bool isRow0 = (tile == 0) && (q == 0);
            if (ln <= 13 && !isRow0)
                arv[q * ASTR + 15 + ln - citq[r]] = f2bf(cwh[r]);
            if (ln == 15)
                arv[q * ASTR + 0] = f2bf(isRow0 ? rsq[r] : p0q[r]);
        }
        MEMBAR();
        { // kt8
            const s8v ap = *(const s8v*)(&ar[ln * ASTR + lg * 8]);
            #pragma unroll
            for (int nt = 0; nt < 4; ++nt) {
                const s8v bv = *(const s8v*)(&Vt[(nt * 16 + ln) * VSTR + 256 + lg * 8]);
                oacc[nt] = mfma_bf16(ap, bv, oacc[nt]);
            }
        }
    }
    // ---- normalize + store (C row = q = 4lg+r, col = d = nt*16+ln) ----
    #pragma unroll
    for (int r = 0; r < 4; ++r) {
        int n = qb + 4 * lg + r;
        if (n < N_) {
            float sc = 1.0f / rsq[r];
            float* orow = out + ((size_t)b * N_ + n) * COUT + h * 64;
            #pragma unroll
            for (int nt = 0; nt < 4; ++nt)
                orow[nt * 16 + ln] = oacc[nt][r] * sc;
        }
    }
}

extern "C" void kernel_launch(void* const* d_in, const int* in_sizes, int n_in,
                              void* d_out, int out_size, void* d_ws, size_t ws_size,
                              hipStream_t stream) {
    const float* x   = (const float*)d_in[0];
    const float* tkv = (const float*)d_in[1];
    const float* tkh = (const float*)d_in[2];
    const float* tvv = (const float*)d_in[3];
    const float* tvh = (const float*)d_in[4];
    float* o = (float*)d_out;
    attn_super<<<dim3(64 * H_), dim3(1024), 0, stream>>>(x, tkv, tkh, tvv, tvh, o);
}

// Round 8
// 71.654 us; speedup vs baseline: 1.7047x; 1.0514x over previous
//
#include <hip/hip_runtime.h>

typedef float  f4v   __attribute__((ext_vector_type(4)));
typedef float  f32x4 __attribute__((ext_vector_type(4)));
typedef short  s8v   __attribute__((ext_vector_type(8)));
typedef short  s4v   __attribute__((ext_vector_type(4)));
typedef __bf16 bf16x8 __attribute__((ext_vector_type(8)));

#define N_   197
#define H_   12
#define CIN  3072
#define COUT 1024
#define VSTR 296   // Vt row stride (shorts)
#define ASTR 72    // arena row stride (shorts)
#define BSTR 40    // Bext row stride (shorts): 80 B, 16B-aligned, 20 dw % 32 -> spread

#define MEMBAR() asm volatile("" ::: "memory")

__device__ __forceinline__ unsigned short f2bf(float f) {
    unsigned u = __float_as_uint(f);
    u += 0x7FFFu + ((u >> 16) & 1u);
    return (unsigned short)(u >> 16);
}
__device__ __forceinline__ float bf2f(unsigned short s) {
    return __uint_as_float(((unsigned)s) << 16);
}
__device__ __forceinline__ f32x4 mfma_bf16(s8v a, s8v b, f32x4 c) {
    return __builtin_amdgcn_mfma_f32_16x16x32_bf16(
        __builtin_bit_cast(bf16x8, a), __builtin_bit_cast(bf16x8, b), c, 0, 0, 0);
}
__device__ __forceinline__ void st4f(volatile unsigned short* p, float a, float b, float c, float d) {
    s4v v;
    v[0] = (short)f2bf(a); v[1] = (short)f2bf(b);
    v[2] = (short)f2bf(c); v[3] = (short)f2bf(d);
    *(volatile s4v*)p = v;
}
__device__ __forceinline__ void st4z(volatile unsigned short* p) {
    s4v v = {0, 0, 0, 0};
    *(volatile s4v*)p = v;
}

// One block per (b,h), 1024 threads = 16 waves. Wave w (<13) owns q-tile w.
// Swapped QK^T with FUSED rel-pos bias: per-q-row pre-shifted tables qt2 make
// bias = (one-hot Bext[k]) . qt2[q] -> a third MFMA chained into the S acc.
// Softmax is then pure exp+sum in registers (no LDS gathers, no index VALU).
// Bins (rel-pos value einsum) via indicator MFMA: wv = P*Sv, wh = P*Sh.
__launch_bounds__(1024, 4)
__global__ void attn_super(const float* __restrict__ x,
                           const float* __restrict__ tkv,
                           const float* __restrict__ tkh,
                           const float* __restrict__ tvv,
                           const float* __restrict__ tvh,
                           float* __restrict__ out) {
    __shared__ __align__(16) unsigned short Kl[272 * 72];
    __shared__ __align__(16) unsigned short Vt[64 * VSTR];
    __shared__ __align__(16) unsigned short AR[16][16 * ASTR];
    __shared__ __align__(16) unsigned short INDv[16 * 224];
    __shared__ __align__(16) unsigned short INDh[16 * 224];
    __shared__ __align__(16) unsigned short Bext[224 * BSTR];

    const int bid = blockIdx.x;
    const int b = bid / H_, h = bid % H_;
    const int tid = threadIdx.x;
    const int w  = tid >> 6;       // wave 0..15
    const int l  = tid & 63;
    const int lg = l >> 4;         // 16-lane group
    const int ln = l & 15;

    const float* xb = x + (size_t)b * N_ * CIN;

    // ---- zero-pad output channels [768,1024) (h<4 blocks): issue early ----
    if (h < 4) {
        float* oz = out + (size_t)b * N_ * COUT + 768 + h * 64;
        for (int idx = tid; idx < N_ * 16; idx += 1024) {
            int row = idx >> 4, c4 = idx & 15;
            f4v z = {0.f, 0.f, 0.f, 0.f};
            *(f4v*)(oz + (size_t)row * COUT + c4 * 4) = z;
        }
    }

    // ---- PROLOGUE: issue ALL global loads (K, then Q, then V) ----
    f4v kr[5];
    #pragma unroll
    for (int it = 0; it < 5; ++it) {
        int idx = it * 1024 + tid;
        bool a5 = (it < 4) || (tid < 256);       // 272*16 = 4352
        int row = idx >> 4, d0 = (idx & 15) * 4;
        f4v v = {0.f, 0.f, 0.f, 0.f};
        if (a5) {
            if (row < N_)                     v = *(const f4v*)(xb + (size_t)row * CIN + 768 + h * 64 + d0);
            else if (row >= 208 && row < 238) v = *(const f4v*)(tkv + (row - 208) * 64 + d0);
            else if (row >= 240 && row < 270) v = *(const f4v*)(tkh + (row - 240) * 64 + d0);
        }
        kr[it] = v;
    }
    f4v q1[2], q2[2];
    if (w < 13) {
        int qrow = w * 16 + ln; if (qrow > 196) qrow = 196;
        const float* qp = xb + (size_t)qrow * CIN + h * 64;
        #pragma unroll
        for (int s2 = 0; s2 < 2; ++s2) {
            q1[s2] = *(const f4v*)(qp + s2 * 32 + lg * 8);
            q2[s2] = *(const f4v*)(qp + s2 * 32 + lg * 8 + 4);
        }
    }
    f4v vr[5];
    #pragma unroll
    for (int it = 0; it < 5; ++it) {
        int idx = it * 1024 + tid;
        bool a5 = (it < 4) || (tid < 512);       // 288*16 = 4608
        int j = idx % 288, d0 = (idx / 288) * 4;
        f4v v = {0.f, 0.f, 0.f, 0.f};
        if (a5) {
            if (j < N_)                     v = *(const f4v*)(xb + (size_t)j * CIN + 1536 + h * 64 + d0);
            else if (j >= 224 && j < 254)   v = *(const f4v*)(tvv + (j - 224) * 64 + d0);
            else if (j >= 256 && j < 286)   v = *(const f4v*)(tvh + (j - 256) * 64 + d0);
        }
        vr[it] = v;
    }

    // ---- write K -> LDS (waits only on K loads) ----
    #pragma unroll
    for (int it = 0; it < 5; ++it) {
        int idx = it * 1024 + tid;
        bool a5 = (it < 4) || (tid < 256);
        if (a5) {
            int row = idx >> 4, d0 = (idx & 15) * 4;
            f4v v = kr[it];
            s4v pk;
            pk[0] = (short)f2bf(v[0]); pk[1] = (short)f2bf(v[1]);
            pk[2] = (short)f2bf(v[2]); pk[3] = (short)f2bf(v[3]);
            *(s4v*)(&Kl[row * 72 + d0]) = pk;
        }
    }
    // ---- build indicator tables (VALU-only) ----
    for (int idx = tid; idx < 16 * 224; idx += 1024) {
        int m = idx / 224, k = idx % 224;
        int km1 = k - 1;
        bool kv = (k >= 1 && k <= 196);
        INDv[idx] = (kv && (km1 / 14) == m) ? (unsigned short)0x3F80 : (unsigned short)0;
        INDh[idx] = (kv && (km1 % 14) == m) ? (unsigned short)0x3F80 : (unsigned short)0;
    }
    // ---- build Bext one-hot bias matrix [224][BSTR], cols 0..31 used ----
    for (int idx = tid; idx < 224 * 32; idx += 1024) {
        int k = idx >> 5, c = idx & 31;
        unsigned short v = 0;
        if (k >= 1 && k <= 196) {
            int mj = (k - 1) / 14, cj = (k - 1) - mj * 14;
            if (c == mj || c == 16 + cj) v = (unsigned short)0x3F80;
        } else if (k == 0) {
            if (c == 15 || c == 31) v = (unsigned short)0x3F80;
        }
        Bext[k * BSTR + c] = v;
    }
    __syncthreads();   // B1: Kl + IND + Bext ready

    const int tile = w, qb = tile * 16;
    const unsigned short* ar = &AR[w][0];
    volatile unsigned short* arv = &AR[w][0];

    f32x4 S[13];
    float rsq[4], p0q[4];
    int ritq[4], citq[4];
    if (w < 13) {
        // per-lane shift constants for q-row i = qb + ln
        const int iL  = qb + ln;
        const int im1 = (iL > 0) ? iL - 1 : 0;
        const int rit = im1 / 14;
        const int cit = im1 - rit * 14;

        // Q frags from prefetched regs (pre-scaled 1/8)
        s8v aq[2];
        #pragma unroll
        for (int s2 = 0; s2 < 2; ++s2) {
            #pragma unroll
            for (int e = 0; e < 4; ++e) {
                aq[s2][e]     = (short)f2bf(q1[s2][e] * 0.125f);
                aq[s2][e + 4] = (short)f2bf(q2[s2][e] * 0.125f);
            }
        }
        // ---- table tiles -> pre-shifted qt2 (arena cols 0..31, row = q = ln) ----
        float spv = 0.f, sph = 0.f;
        #pragma unroll
        for (int tt = 0; tt < 4; ++tt) {
            f32x4 acc = {0.f, 0.f, 0.f, 0.f};
            #pragma unroll
            for (int s2 = 0; s2 < 2; ++s2) {
                const s8v bk = *(const s8v*)(&Kl[((13 + tt) * 16 + ln) * 72 + s2 * 32 + lg * 8]);
                acc = mfma_bf16(bk, aq[s2], acc);
            }
            const bool isV  = (tt < 2);
            const int mbase = (tt & 1) * 16;
            const int shift = isV ? rit : cit;
            const int cbase = isV ? 0 : 16;
            const bool skip0 = (tile == 0 && ln == 0);   // row q==0 handled specially
            #pragma unroll
            for (int r = 0; r < 4; ++r) {
                int m = mbase + 4 * lg + r;
                int t = m + shift - 15;
                if (!skip0 && m < 30 && t >= 0 && t < 15)
                    arv[ln * ASTR + cbase + t] = f2bf(acc[r]);
                if (!skip0 && m == 0)
                    arv[ln * ASTR + cbase + 15] = f2bf(acc[r]);   // k==0 slot
            }
            if (tile == 0 && l == 0) {
                if (tt == 0) spv = acc[0];
                if (tt == 2) sph = acc[0];
            }
        }
        // row q==0 (i==0): bias is qtv[0][0]+qth[0][0] for ALL k -> constant rows
        if (tile == 0 && l == 0) {
            unsigned short v0 = f2bf(spv), h0 = f2bf(sph);
            #pragma unroll
            for (int t = 0; t < 16; ++t) {
                arv[t] = v0;
                arv[16 + t] = h0;
            }
        }
        MEMBAR();   // qt2 scatter writes -> aq2 vector read
        const s8v aq2 = *(const s8v*)(&ar[ln * ASTR + lg * 8]);
        // ---- swapped QK^T with fused bias: S = Bext.qt2 + K.Q ----
        #pragma unroll
        for (int ct = 0; ct < 13; ++ct) {
            const s8v be = *(const s8v*)(&Bext[(ct * 16 + ln) * BSTR + lg * 8]);
            f32x4 acc = {0.f, 0.f, 0.f, 0.f};
            acc = mfma_bf16(be, aq2, acc);
            #pragma unroll
            for (int s2 = 0; s2 < 2; ++s2) {
                const s8v bk = *(const s8v*)(&Kl[(ct * 16 + ln) * 72 + s2 * 32 + lg * 8]);
                acc = mfma_bf16(bk, aq[s2], acc);
            }
            S[ct] = acc;
        }
    }
    // ---- write V -> LDS (ALL waves; V-load latency hid under table+QK) ----
    #pragma unroll
    for (int it = 0; it < 5; ++it) {
        int idx = it * 1024 + tid;
        bool a5 = (it < 4) || (tid < 512);
        if (a5) {
            int j = idx % 288, d0 = (idx / 288) * 4;
            f4v v = vr[it];
            #pragma unroll
            for (int e = 0; e < 4; ++e)
                Vt[(d0 + e) * VSTR + j] = f2bf(v[e]);
        }
    }

    if (w < 13) {
        // ---- softmax: pure exp + row-sum (bias already in S) ----
        float rs4[4] = {0.f, 0.f, 0.f, 0.f};
        #pragma unroll
        for (int ct = 0; ct < 13; ++ct) {
            #pragma unroll
            for (int r = 0; r < 4; ++r) {
                float p = __expf(S[ct][r]);
                if (ct == 12) { if (4 * lg + r > 4) p = 0.f; }   // k>196 invalid
                S[ct][r] = p;
                rs4[r] += p;
            }
        }
        float rs = (rs4[0] + rs4[1]) + (rs4[2] + rs4[3]);
        rs += __shfl_xor(rs, 16);
        rs += __shfl_xor(rs, 32);
        float p00 = S[0][0];
        #pragma unroll
        for (int r = 0; r < 4; ++r) {
            rsq[r] = __shfl(rs,  4 * lg + r);
            p0q[r] = __shfl(p00, 4 * lg + r);
        }
        #pragma unroll
        for (int r = 0; r < 4; ++r) {
            int qr2 = qb + 4 * lg + r;
            int im  = (qr2 > 0) ? qr2 - 1 : 0;
            ritq[r] = im / 14;
            citq[r] = im - ritq[r] * 14;
        }
    }
    __syncthreads();   // B2: Vt ready

    if (w >= 13) return;

    // ---- PV + bins via sliding 64-col arena window ----
    f32x4 oacc[4];
    #pragma unroll
    for (int nt = 0; nt < 4; ++nt) { f32x4 z = {0.f,0.f,0.f,0.f}; oacc[nt] = z; }
    f32x4 cwv = {0.f,0.f,0.f,0.f}, cwh = {0.f,0.f,0.f,0.f};

    #pragma unroll
    for (int win = 0; win < 3; ++win) {         // k 0..63, 64..127, 128..191
        MEMBAR();
        #pragma unroll
        for (int cc = 0; cc < 4; ++cc) {
            int ct = win * 4 + cc;
            st4f(&arv[ln * ASTR + cc * 16 + 4 * lg], S[ct][0], S[ct][1], S[ct][2], S[ct][3]);
        }
        MEMBAR();
        #pragma unroll
        for (int kk = 0; kk < 2; ++kk) {
            int kt = win * 2 + kk;
            const s8v ap = *(const s8v*)(&ar[ln * ASTR + kk * 32 + lg * 8]);
            #pragma unroll
            for (int nt = 0; nt < 4; ++nt) {
                const s8v bv = *(const s8v*)(&Vt[(nt * 16 + ln) * VSTR + kt * 32 + lg * 8]);
                oacc[nt] = mfma_bf16(ap, bv, oacc[nt]);
            }
            const s8v bi = *(const s8v*)(&INDv[ln * 224 + kt * 32 + lg * 8]);
            cwv = mfma_bf16(ap, bi, cwv);
            const s8v bh = *(const s8v*)(&INDh[ln * 224 + kt * 32 + lg * 8]);
            cwh = mfma_bf16(ap, bh, cwh);
        }
    }
    { // window 3: k 192..255  (P ct12 | zeros | wv bins)
        MEMBAR();
        st4f(&arv[ln * ASTR + 4 * lg], S[12][0], S[12][1], S[12][2], S[12][3]);
        st4z(&arv[ln * ASTR + 16 + 4 * lg]);
        st4z(&arv[ln * ASTR + 32 + lg * 8]);
        st4z(&arv[ln * ASTR + 36 + lg * 8]);
        MEMBAR();
        { // kt6 (k 192..223)
            const s8v ap = *(const s8v*)(&ar[ln * ASTR + lg * 8]);
            #pragma unroll
            for (int nt = 0; nt < 4; ++nt) {
                const s8v bv = *(const s8v*)(&Vt[(nt * 16 + ln) * VSTR + 192 + lg * 8]);
                oacc[nt] = mfma_bf16(ap, bv, oacc[nt]);
            }
            const s8v bi = *(const s8v*)(&INDv[ln * 224 + 192 + lg * 8]);
            cwv = mfma_bf16(ap, bi, cwv);
            const s8v bh = *(const s8v*)(&INDh[ln * 224 + 192 + lg * 8]);
            cwh = mfma_bf16(ap, bh, cwh);
        }
        MEMBAR();
        // scatter wv bins: C_wv[q=4lg+r][m=ln] -> col 32 + (ln - ritq + 15)
        #pragma unroll
        for (int r = 0; r < 4; ++r) {
            int q = 4 * lg + r;
            bool isRow0 = (tile == 0) && (q == 0);
            if (ln <= 13 && !isRow0)
                arv[q * ASTR + 47 + ln - ritq[r]] = f2bf(cwv[r]);
            if (ln == 15)
                arv[q * ASTR + 32] = f2bf(isRow0 ? rsq[r] : p0q[r]);
        }
        MEMBAR();
        { // kt7 (k 224..255 = tv_v bins)
            const s8v ap = *(const s8v*)(&ar[ln * ASTR + 32 + lg * 8]);
            #pragma unroll
            for (int nt = 0; nt < 4; ++nt) {
                const s8v bv = *(const s8v*)(&Vt[(nt * 16 + ln) * VSTR + 224 + lg * 8]);
                oacc[nt] = mfma_bf16(ap, bv, oacc[nt]);
            }
        }
    }
    { // window 4: k 256..287 (wh bins)
        MEMBAR();
        st4z(&arv[ln * ASTR + lg * 8]);
        st4z(&arv[ln * ASTR + 4 + lg * 8]);
        MEMBAR();
        #pragma unroll
        for (int r = 0; r < 4; ++r) {
            int q = 4 * lg + r;
            bool isRow0 = (tile == 0) && (q == 0);
            if (ln <= 13 && !isRow0)
                arv[q * ASTR + 15 + ln - citq[r]] = f2bf(cwh[r]);
            if (ln == 15)
                arv[q * ASTR + 0] = f2bf(isRow0 ? rsq[r] : p0q[r]);
        }
        MEMBAR();
        { // kt8
            const s8v ap = *(const s8v*)(&ar[ln * ASTR + lg * 8]);
            #pragma unroll
            for (int nt = 0; nt < 4; ++nt) {
                const s8v bv = *(const s8v*)(&Vt[(nt * 16 + ln) * VSTR + 256 + lg * 8]);
                oacc[nt] = mfma_bf16(ap, bv, oacc[nt]);
            }
        }
    }
    // ---- normalize + store (C row = q = 4lg+r, col = d = nt*16+ln) ----
    #pragma unroll
    for (int r = 0; r < 4; ++r) {
        int n = qb + 4 * lg + r;
        if (n < N_) {
            float sc = 1.0f / rsq[r];
            float* orow = out + ((size_t)b * N_ + n) * COUT + h * 64;
            #pragma unroll
            for (int nt = 0; nt < 4; ++nt)
                orow[nt * 16 + ln] = oacc[nt][r] * sc;
        }
    }
}

extern "C" void kernel_launch(void* const* d_in, const int* in_sizes, int n_in,
                              void* d_out, int out_size, void* d_ws, size_t ws_size,
                              hipStream_t stream) {
    const float* x   = (const float*)d_in[0];
    const float* tkv = (const float*)d_in[1];
    const float* tkh = (const float*)d_in[2];
    const float* tvv = (const float*)d_in[3];
    const float* tvh = (const float*)d_in[4];
    float* o = (float*)d_out;
    attn_super<<<dim3(64 * H_), dim3(1024), 0, stream>>>(x, tkv, tkh, tvv, tvh, o);
}